// Round 1
// baseline (121336.060 us; speedup 1.0000x reference)
//
#include <hip/hip_runtime.h>

#define BATCH  32768
#define HID    512
#define BM     64
#define TPB    512
#define NSTEP  60

using f32x4 = __attribute__((ext_vector_type(4))) float;
using s16x8 = __attribute__((ext_vector_type(8))) short;

__device__ __forceinline__ unsigned short f2bf(float f) {
    unsigned u = __builtin_bit_cast(unsigned, f);
    u += 0x7fffu + ((u >> 16) & 1u);
    return (unsigned short)(u >> 16);
}
__device__ __forceinline__ float sigm(float x) { return 1.0f / (1.0f + __expf(-x)); }
__device__ __forceinline__ float tanh_(float x) { return 1.0f - 2.0f / (__expf(2.0f * x) + 1.0f); }

// ---------------- weight packing ----------------
// P1: w_hh0  -> [tile(g*32+c)][ks 0..15][lane][8]  (1,048,576 bf16)
// P2: [w_ih1 | w_hh1] -> [tile][ks 0..31][lane][8] (2,097,152 bf16)
// PI: [w_init_h | w_init_c] -> [tile(s*32+c)][ks 0..15][lane][8] (524,288 bf16)
// b1 = b_ih0 + b_hh0 ; b2 = b_ih1 + b_hh1
__global__ void pack_kernel(const float* __restrict__ w_hh0, const float* __restrict__ w_ih1,
                            const float* __restrict__ w_hh1, const float* __restrict__ w_init_h,
                            const float* __restrict__ w_init_c,
                            const float* __restrict__ b_ih0, const float* __restrict__ b_hh0,
                            const float* __restrict__ b_ih1, const float* __restrict__ b_hh1,
                            unsigned short* __restrict__ P1, unsigned short* __restrict__ P2,
                            unsigned short* __restrict__ PI,
                            float* __restrict__ b1, float* __restrict__ b2)
{
    int idx = blockIdx.x * 256 + threadIdx.x;
    if (idx < 1048576) {
        int el = idx & 511, fr = idx >> 9;
        int ks = fr & 15, tile = fr >> 4;
        int g = tile >> 5, c = tile & 31;
        int lane = el >> 3, e = el & 7;
        int n = g * 512 + c * 16 + (lane & 15);
        int k = ks * 32 + (lane >> 4) * 8 + e;
        P1[idx] = f2bf(w_hh0[n * 512 + k]);
        return;
    }
    int i2 = idx - 1048576;
    if (i2 >= 0 && i2 < 2097152) {
        int el = i2 & 511, fr = i2 >> 9;
        int ks = fr & 31, tile = fr >> 5;
        int g = tile >> 5, c = tile & 31;
        int lane = el >> 3, e = el & 7;
        int n = g * 512 + c * 16 + (lane & 15);
        int kk = (ks & 15) * 32 + (lane >> 4) * 8 + e;
        float v = (ks < 16) ? w_ih1[n * 512 + kk] : w_hh1[n * 512 + kk];
        P2[i2] = f2bf(v);
        return;
    }
    int i3 = idx - (1048576 + 2097152);
    if (i3 >= 0 && i3 < 524288) {
        int el = i3 & 511, fr = i3 >> 9;
        int ks = fr & 15, tile = fr >> 4;
        int s = tile >> 5, c = tile & 31;
        int lane = el >> 3, e = el & 7;
        int n = c * 16 + (lane & 15);
        int k = ks * 32 + (lane >> 4) * 8 + e;
        float v = s ? w_init_c[n * 512 + k] : w_init_h[n * 512 + k];
        PI[i3] = f2bf(v);
        return;
    }
    int i4 = idx - (1048576 + 2097152 + 524288);
    if (i4 >= 0 && i4 < 2048) b1[i4] = b_ih0[i4] + b_hh0[i4];
    else if (i4 >= 2048 && i4 < 4096) b2[i4 - 2048] = b_ih1[i4 - 2048] + b_hh1[i4 - 2048];
}

// ---------------- init: h0 = h@w_init_h^T + b ; c0 likewise; both layers ----------------
__global__ __launch_bounds__(TPB, 2) void init_kernel(
    const float* __restrict__ hin, const unsigned short* __restrict__ PI,
    const float* __restrict__ b_init_h, const float* __restrict__ b_init_c,
    unsigned short* __restrict__ h1s, unsigned short* __restrict__ h2s,
    float* __restrict__ c1s, float* __restrict__ c2s, float* __restrict__ xs)
{
    __shared__ unsigned short bufA[BM * HID];
    const int tid = threadIdx.x, lane = tid & 63, wave = tid >> 6;
    const int m0 = blockIdx.x * BM;
    const int l15 = lane & 15, lg = lane >> 4;
    const int swz = (lane & 7) << 4;

    // stage input h (fp32) -> bufA (bf16, XOR-swizzled rows)
    for (int j = 0; j < 16; ++j) {
        int e = tid * 4 + j * 2048;
        int row = e >> 9, col = e & 511;
        float4 v = *(const float4*)(hin + (size_t)(m0 + row) * HID + col);
        ushort4 w;
        w.x = f2bf(v.x); w.y = f2bf(v.y); w.z = f2bf(v.z); w.w = f2bf(v.w);
        int L = (row * 1024 + col * 2) ^ ((row & 7) << 4);
        *(ushort4*)((char*)bufA + L) = w;
    }
    if (tid < 2 * BM) xs[m0 * 2 + tid] = 0.0f;
    __syncthreads();

    #pragma unroll 1
    for (int cc = 0; cc < 4; ++cc) {
        int c = wave * 4 + cc;
        int nc = c * 16 + l15;
        f32x4 acc[4][2];
        #pragma unroll
        for (int rt = 0; rt < 4; ++rt)
            #pragma unroll
            for (int s = 0; s < 2; ++s)
                #pragma unroll
                for (int r = 0; r < 4; ++r) acc[rt][s][r] = 0.0f;

        #pragma unroll
        for (int ks = 0; ks < 16; ++ks) {
            s16x8 a[4];
            #pragma unroll
            for (int rt = 0; rt < 4; ++rt) {
                int ao = (rt * 16 + l15) * 1024 + ((ks * 64 + lg * 16) ^ swz);
                a[rt] = *(const s16x8*)((const char*)bufA + ao);
            }
            #pragma unroll
            for (int s = 0; s < 2; ++s) {
                s16x8 b = ((const s16x8*)PI)[((s * 32 + c) * 16 + ks) * 64 + lane];
                #pragma unroll
                for (int rt = 0; rt < 4; ++rt)
                    acc[rt][s] = __builtin_amdgcn_mfma_f32_16x16x32_bf16(a[rt], b, acc[rt][s], 0, 0, 0);
            }
        }
        float bh = b_init_h[nc], bc = b_init_c[nc];
        #pragma unroll
        for (int rt = 0; rt < 4; ++rt)
            #pragma unroll
            for (int r = 0; r < 4; ++r) {
                int m = m0 + rt * 16 + lg * 4 + r;
                float hv = acc[rt][0][r] + bh;
                float cv = acc[rt][1][r] + bc;
                unsigned short hb = f2bf(hv);
                size_t o = (size_t)m * HID + nc;
                h1s[o] = hb; h2s[o] = hb;
                c1s[o] = cv; c2s[o] = cv;
            }
    }
}

// ---------------- fused per-timestep kernel ----------------
__global__ __launch_bounds__(TPB, 2) void step_kernel(
    unsigned short* __restrict__ h1s, unsigned short* __restrict__ h2s,
    float* __restrict__ c1s, float* __restrict__ c2s, float* __restrict__ xs,
    const unsigned short* __restrict__ P1, const unsigned short* __restrict__ P2,
    const float* __restrict__ b1, const float* __restrict__ b2,
    const float* __restrict__ w_ih0, const float* __restrict__ w_out,
    const float* __restrict__ b_out, float* __restrict__ out, int t)
{
    __shared__ unsigned short bufA[BM * HID];
    __shared__ unsigned short bufB[BM * HID];
    __shared__ float xls[BM * 2];
    __shared__ float pls[BM * 2];

    const int tid = threadIdx.x, lane = tid & 63, wave = tid >> 6;
    const int m0 = blockIdx.x * BM;
    const int l15 = lane & 15, lg = lane >> 4;
    const int swz = (lane & 7) << 4;

    // stage h1_old -> bufA (swizzled)
    {
        int wofs = (tid * 16) ^ ((wave & 7) << 4);
        const char* src = (const char*)(h1s + (size_t)m0 * HID);
        #pragma unroll
        for (int j = 0; j < 8; ++j) {
            uint4 v = *(const uint4*)(src + tid * 16 + j * 8192);
            *(uint4*)((char*)bufA + wofs + j * 8192) = v;
        }
    }
    if (tid < 2 * BM) { xls[tid] = xs[m0 * 2 + tid]; pls[tid] = 0.0f; }
    __syncthreads();

    // -------- layer 1: gates1 = h1@w_hh0^T + x@w_ih0^T + b1 --------
    #pragma unroll 1
    for (int cc = 0; cc < 4; ++cc) {
        int c = wave * 4 + cc;
        int nc = c * 16 + l15;
        f32x4 acc[4][4];
        float bg[4], wi0[4], wi1[4];
        #pragma unroll
        for (int g = 0; g < 4; ++g) {
            bg[g]  = b1[g * 512 + nc];
            wi0[g] = w_ih0[(g * 512 + nc) * 2 + 0];
            wi1[g] = w_ih0[(g * 512 + nc) * 2 + 1];
        }
        #pragma unroll
        for (int rt = 0; rt < 4; ++rt)
            #pragma unroll
            for (int r = 0; r < 4; ++r) {
                int ml = rt * 16 + lg * 4 + r;
                float x0 = xls[ml * 2 + 0], x1 = xls[ml * 2 + 1];
                #pragma unroll
                for (int g = 0; g < 4; ++g)
                    acc[rt][g][r] = bg[g] + x0 * wi0[g] + x1 * wi1[g];
            }
        #pragma unroll
        for (int ks = 0; ks < 16; ++ks) {
            s16x8 a[4];
            #pragma unroll
            for (int rt = 0; rt < 4; ++rt) {
                int ao = (rt * 16 + l15) * 1024 + ((ks * 64 + lg * 16) ^ swz);
                a[rt] = *(const s16x8*)((const char*)bufA + ao);
            }
            #pragma unroll
            for (int g = 0; g < 4; ++g) {
                s16x8 b = ((const s16x8*)P1)[((g * 32 + c) * 16 + ks) * 64 + lane];
                #pragma unroll
                for (int rt = 0; rt < 4; ++rt)
                    acc[rt][g] = __builtin_amdgcn_mfma_f32_16x16x32_bf16(a[rt], b, acc[rt][g], 0, 0, 0);
            }
        }
        #pragma unroll
        for (int rt = 0; rt < 4; ++rt)
            #pragma unroll
            for (int r = 0; r < 4; ++r) {
                int ml = rt * 16 + lg * 4 + r;
                int m = m0 + ml;
                float iv = sigm(acc[rt][0][r]);
                float fv = sigm(acc[rt][1][r]);
                float gv = tanh_(acc[rt][2][r]);
                float ov = sigm(acc[rt][3][r]);
                size_t o = (size_t)m * HID + nc;
                float cold = c1s[o];
                float cn = fv * cold + iv * gv;
                c1s[o] = cn;
                float hn = ov * tanh_(cn);
                unsigned short hb = f2bf(hn);
                h1s[o] = hb;
                int L = ml * 1024 + nc * 2;
                *(unsigned short*)((char*)bufB + (L ^ ((ml & 7) << 4))) = hb;
            }
    }
    __syncthreads();

    // stage h2_old -> bufA (swizzled)
    {
        int wofs = (tid * 16) ^ ((wave & 7) << 4);
        const char* src = (const char*)(h2s + (size_t)m0 * HID);
        #pragma unroll
        for (int j = 0; j < 8; ++j) {
            uint4 v = *(const uint4*)(src + tid * 16 + j * 8192);
            *(uint4*)((char*)bufA + wofs + j * 8192) = v;
        }
    }
    __syncthreads();

    // -------- layer 2: gates2 = h1_new@w_ih1^T + h2@w_hh1^T + b2 ; pred --------
    #pragma unroll 1
    for (int cc = 0; cc < 4; ++cc) {
        int c = wave * 4 + cc;
        int nc = c * 16 + l15;
        f32x4 acc[4][4];
        #pragma unroll
        for (int g = 0; g < 4; ++g) {
            float bgv = b2[g * 512 + nc];
            #pragma unroll
            for (int rt = 0; rt < 4; ++rt)
                #pragma unroll
                for (int r = 0; r < 4; ++r)
                    acc[rt][g][r] = bgv;
        }
        #pragma unroll
        for (int ks = 0; ks < 32; ++ks) {
            const char* abuf = (ks < 16) ? (const char*)bufB : (const char*)bufA;
            int kk = ks & 15;
            s16x8 a[4];
            #pragma unroll
            for (int rt = 0; rt < 4; ++rt) {
                int ao = (rt * 16 + l15) * 1024 + ((kk * 64 + lg * 16) ^ swz);
                a[rt] = *(const s16x8*)(abuf + ao);
            }
            #pragma unroll
            for (int g = 0; g < 4; ++g) {
                s16x8 b = ((const s16x8*)P2)[((g * 32 + c) * 32 + ks) * 64 + lane];
                #pragma unroll
                for (int rt = 0; rt < 4; ++rt)
                    acc[rt][g] = __builtin_amdgcn_mfma_f32_16x16x32_bf16(a[rt], b, acc[rt][g], 0, 0, 0);
            }
        }
        float wo0 = w_out[nc], wo1 = w_out[512 + nc];
        #pragma unroll
        for (int rt = 0; rt < 4; ++rt)
            #pragma unroll
            for (int r = 0; r < 4; ++r) {
                int ml = rt * 16 + lg * 4 + r;
                int m = m0 + ml;
                float iv = sigm(acc[rt][0][r]);
                float fv = sigm(acc[rt][1][r]);
                float gv = tanh_(acc[rt][2][r]);
                float ov = sigm(acc[rt][3][r]);
                size_t o = (size_t)m * HID + nc;
                float cold = c2s[o];
                float cn = fv * cold + iv * gv;
                c2s[o] = cn;
                float hn = ov * tanh_(cn);
                h2s[o] = f2bf(hn);
                float p0 = hn * wo0, p1 = hn * wo1;
                #pragma unroll
                for (int s = 1; s < 16; s <<= 1) {
                    p0 += __shfl_xor(p0, s, 64);
                    p1 += __shfl_xor(p1, s, 64);
                }
                if (l15 == 0) {
                    atomicAdd(&pls[ml * 2 + 0], p0);
                    atomicAdd(&pls[ml * 2 + 1], p1);
                }
            }
    }
    __syncthreads();
    if (tid < 2 * BM) {
        int ml = tid >> 1, j = tid & 1;
        float p = pls[tid] + b_out[j];
        out[(size_t)(m0 + ml) * (2 * NSTEP) + t * 2 + j] = p;
        xs[m0 * 2 + tid] = p;
    }
}

extern "C" void kernel_launch(void* const* d_in, const int* in_sizes, int n_in,
                              void* d_out, int out_size, void* d_ws, size_t ws_size,
                              hipStream_t stream)
{
    (void)in_sizes; (void)n_in; (void)out_size; (void)ws_size;
    const float* h        = (const float*)d_in[0];
    const float* w_init_h = (const float*)d_in[1];
    const float* b_init_h = (const float*)d_in[2];
    const float* w_init_c = (const float*)d_in[3];
    const float* b_init_c = (const float*)d_in[4];
    const float* w_ih0    = (const float*)d_in[5];
    const float* w_hh0    = (const float*)d_in[6];
    const float* b_ih0    = (const float*)d_in[7];
    const float* b_hh0    = (const float*)d_in[8];
    const float* w_ih1    = (const float*)d_in[9];
    const float* w_hh1    = (const float*)d_in[10];
    const float* b_ih1    = (const float*)d_in[11];
    const float* b_hh1    = (const float*)d_in[12];
    const float* w_out    = (const float*)d_in[13];
    const float* b_out    = (const float*)d_in[14];
    float* out = (float*)d_out;

    char* ws = (char*)d_ws;
    unsigned short* h1s = (unsigned short*)(ws + 0);
    unsigned short* h2s = (unsigned short*)(ws + 33554432);
    float* c1s          = (float*)(ws + 67108864);
    float* c2s          = (float*)(ws + 134217728);
    float* xs           = (float*)(ws + 201326592);
    unsigned short* P1  = (unsigned short*)(ws + 201588736);
    unsigned short* P2  = (unsigned short*)(ws + 203685888);
    unsigned short* PI  = (unsigned short*)(ws + 207880192);
    float* b1           = (float*)(ws + 208928768);
    float* b2           = (float*)(ws + 208936960);

    pack_kernel<<<14352, 256, 0, stream>>>(w_hh0, w_ih1, w_hh1, w_init_h, w_init_c,
                                           b_ih0, b_hh0, b_ih1, b_hh1, P1, P2, PI, b1, b2);
    init_kernel<<<BATCH / BM, TPB, 0, stream>>>(h, PI, b_init_h, b_init_c, h1s, h2s, c1s, c2s, xs);
    for (int t = 0; t < NSTEP; ++t)
        step_kernel<<<BATCH / BM, TPB, 0, stream>>>(h1s, h2s, c1s, c2s, xs, P1, P2, b1, b2,
                                                    w_ih0, w_out, b_out, out, t);
}

// Round 2
// 119790.393 us; speedup vs baseline: 1.0129x; 1.0129x over previous
//
#include <hip/hip_runtime.h>

#define BATCH  32768
#define HID    512
#define BM     128
#define BMI    64
#define TPB    512
#define NSTEP  60

using f32x4 = __attribute__((ext_vector_type(4))) float;
using s16x8 = __attribute__((ext_vector_type(8))) short;

__device__ __forceinline__ unsigned short f2bf(float f) {
    unsigned u = __builtin_bit_cast(unsigned, f);
    u += 0x7fffu + ((u >> 16) & 1u);
    return (unsigned short)(u >> 16);
}
__device__ __forceinline__ float sigm(float x) { return 1.0f / (1.0f + __expf(-x)); }
__device__ __forceinline__ float tanh_(float x) { return 1.0f - 2.0f / (__expf(2.0f * x) + 1.0f); }

// ---------------- weight packing (unchanged from r1, passed) ----------------
__global__ void pack_kernel(const float* __restrict__ w_hh0, const float* __restrict__ w_ih1,
                            const float* __restrict__ w_hh1, const float* __restrict__ w_init_h,
                            const float* __restrict__ w_init_c,
                            const float* __restrict__ b_ih0, const float* __restrict__ b_hh0,
                            const float* __restrict__ b_ih1, const float* __restrict__ b_hh1,
                            unsigned short* __restrict__ P1, unsigned short* __restrict__ P2,
                            unsigned short* __restrict__ PI,
                            float* __restrict__ b1, float* __restrict__ b2)
{
    int idx = blockIdx.x * 256 + threadIdx.x;
    if (idx < 1048576) {
        int el = idx & 511, fr = idx >> 9;
        int ks = fr & 15, tile = fr >> 4;
        int g = tile >> 5, c = tile & 31;
        int lane = el >> 3, e = el & 7;
        int n = g * 512 + c * 16 + (lane & 15);
        int k = ks * 32 + (lane >> 4) * 8 + e;
        P1[idx] = f2bf(w_hh0[n * 512 + k]);
        return;
    }
    int i2 = idx - 1048576;
    if (i2 >= 0 && i2 < 2097152) {
        int el = i2 & 511, fr = i2 >> 9;
        int ks = fr & 31, tile = fr >> 5;
        int g = tile >> 5, c = tile & 31;
        int lane = el >> 3, e = el & 7;
        int n = g * 512 + c * 16 + (lane & 15);
        int kk = (ks & 15) * 32 + (lane >> 4) * 8 + e;
        float v = (ks < 16) ? w_ih1[n * 512 + kk] : w_hh1[n * 512 + kk];
        P2[i2] = f2bf(v);
        return;
    }
    int i3 = idx - (1048576 + 2097152);
    if (i3 >= 0 && i3 < 524288) {
        int el = i3 & 511, fr = i3 >> 9;
        int ks = fr & 15, tile = fr >> 4;
        int s = tile >> 5, c = tile & 31;
        int lane = el >> 3, e = el & 7;
        int n = c * 16 + (lane & 15);
        int k = ks * 32 + (lane >> 4) * 8 + e;
        float v = s ? w_init_c[n * 512 + k] : w_init_h[n * 512 + k];
        PI[i3] = f2bf(v);
        return;
    }
    int i4 = idx - (1048576 + 2097152 + 524288);
    if (i4 >= 0 && i4 < 2048) b1[i4] = b_ih0[i4] + b_hh0[i4];
    else if (i4 >= 2048 && i4 < 4096) b2[i4 - 2048] = b_ih1[i4 - 2048] + b_hh1[i4 - 2048];
}

// ---------------- init (unchanged structure, BMI=64) ----------------
__global__ __launch_bounds__(TPB, 2) void init_kernel(
    const float* __restrict__ hin, const unsigned short* __restrict__ PI,
    const float* __restrict__ b_init_h, const float* __restrict__ b_init_c,
    unsigned short* __restrict__ h1s, unsigned short* __restrict__ h2s,
    float* __restrict__ c1s, float* __restrict__ c2s, float* __restrict__ xs)
{
    __shared__ unsigned short bufA[BMI * HID];
    const int tid = threadIdx.x, lane = tid & 63, wave = tid >> 6;
    const int m0 = blockIdx.x * BMI;
    const int l15 = lane & 15, lg = lane >> 4;
    const int swz = (lane & 7) << 4;

    for (int j = 0; j < 16; ++j) {
        int e = tid * 4 + j * 2048;
        int row = e >> 9, col = e & 511;
        float4 v = *(const float4*)(hin + (size_t)(m0 + row) * HID + col);
        ushort4 w;
        w.x = f2bf(v.x); w.y = f2bf(v.y); w.z = f2bf(v.z); w.w = f2bf(v.w);
        int L = (row * 1024 + col * 2) ^ ((row & 7) << 4);
        *(ushort4*)((char*)bufA + L) = w;
    }
    if (tid < 2 * BMI) xs[m0 * 2 + tid] = 0.0f;
    __syncthreads();

    #pragma unroll 1
    for (int cc = 0; cc < 4; ++cc) {
        int c = wave * 4 + cc;
        int nc = c * 16 + l15;
        f32x4 acc[4][2];
        #pragma unroll
        for (int rt = 0; rt < 4; ++rt)
            #pragma unroll
            for (int s = 0; s < 2; ++s)
                #pragma unroll
                for (int r = 0; r < 4; ++r) acc[rt][s][r] = 0.0f;

        #pragma unroll
        for (int ks = 0; ks < 16; ++ks) {
            s16x8 a[4];
            #pragma unroll
            for (int rt = 0; rt < 4; ++rt) {
                int ao = (rt * 16 + l15) * 1024 + ((ks * 64 + lg * 16) ^ swz);
                a[rt] = *(const s16x8*)((const char*)bufA + ao);
            }
            #pragma unroll
            for (int s = 0; s < 2; ++s) {
                s16x8 b = ((const s16x8*)PI)[((s * 32 + c) * 16 + ks) * 64 + lane];
                #pragma unroll
                for (int rt = 0; rt < 4; ++rt)
                    acc[rt][s] = __builtin_amdgcn_mfma_f32_16x16x32_bf16(a[rt], b, acc[rt][s], 0, 0, 0);
            }
        }
        float bh = b_init_h[nc], bc = b_init_c[nc];
        #pragma unroll
        for (int rt = 0; rt < 4; ++rt)
            #pragma unroll
            for (int r = 0; r < 4; ++r) {
                int m = m0 + rt * 16 + lg * 4 + r;
                float hv = acc[rt][0][r] + bh;
                float cv = acc[rt][1][r] + bc;
                unsigned short hb = f2bf(hv);
                size_t o = (size_t)m * HID + nc;
                h1s[o] = hb; h2s[o] = hb;
                c1s[o] = cv; c2s[o] = cv;
            }
    }
}

// ---------------- fused per-timestep kernel, BM=128 ----------------
__global__ __launch_bounds__(TPB, 2) void step_kernel(
    unsigned short* __restrict__ h1s, unsigned short* __restrict__ h2s,
    float* __restrict__ c1s, float* __restrict__ c2s, float* __restrict__ xs,
    const unsigned short* __restrict__ P1, const unsigned short* __restrict__ P2,
    const float* __restrict__ b1, const float* __restrict__ b2,
    const float* __restrict__ w_ih0, const float* __restrict__ w_out,
    const float* __restrict__ b_out, float* __restrict__ out, int t)
{
    __shared__ unsigned short buf[BM * HID];   // 128 KB; layer1: [128][512], layer2: [64][1024]
    __shared__ float xls[BM * 2];
    __shared__ float pls[BM * 2];

    const int tid = threadIdx.x, lane = tid & 63, wave = tid >> 6;
    const int m0 = blockIdx.x * BM;
    const int l15 = lane & 15, lg = lane >> 4;
    const int swz = (lane & 7) << 4;

    // ---- stage h1_old -> buf [128][512] (swizzled) ----
    {
        const char* src = (const char*)(h1s + (size_t)m0 * HID);
        #pragma unroll
        for (int j = 0; j < 16; ++j) {
            int e = tid * 16 + j * 8192;
            int row = e >> 10, colb = e & 1023;
            uint4 v = *(const uint4*)(src + e);
            *(uint4*)((char*)buf + row * 1024 + (colb ^ ((row & 7) << 4))) = v;
        }
    }
    if (tid < 2 * BM) { xls[tid] = xs[m0 * 2 + tid]; pls[tid] = 0.0f; }
    __syncthreads();

    // -------- layer 1: gates1 = h1@w_hh0^T + x@w_ih0^T + b1 (rt=8) --------
    #pragma unroll 1
    for (int cc = 0; cc < 4; ++cc) {
        int c = wave * 4 + cc;
        int nc = c * 16 + l15;
        f32x4 acc[8][4];
        float bg[4], wi0[4], wi1[4];
        #pragma unroll
        for (int g = 0; g < 4; ++g) {
            bg[g]  = b1[g * 512 + nc];
            wi0[g] = w_ih0[(g * 512 + nc) * 2 + 0];
            wi1[g] = w_ih0[(g * 512 + nc) * 2 + 1];
        }
        #pragma unroll
        for (int rt = 0; rt < 8; ++rt)
            #pragma unroll
            for (int r = 0; r < 4; ++r) {
                int ml = rt * 16 + lg * 4 + r;
                float x0 = xls[ml * 2 + 0], x1 = xls[ml * 2 + 1];
                #pragma unroll
                for (int g = 0; g < 4; ++g)
                    acc[rt][g][r] = bg[g] + x0 * wi0[g] + x1 * wi1[g];
            }
        s16x8 bc[4], bn[4];
        #pragma unroll
        for (int g = 0; g < 4; ++g)
            bc[g] = ((const s16x8*)P1)[((g * 32 + c) * 16 + 0) * 64 + lane];
        #pragma unroll
        for (int ks = 0; ks < 16; ++ks) {
            s16x8 a[8];
            #pragma unroll
            for (int rt = 0; rt < 8; ++rt) {
                int ao = (rt * 16 + l15) * 1024 + ((ks * 64 + lg * 16) ^ swz);
                a[rt] = *(const s16x8*)((const char*)buf + ao);
            }
            if (ks < 15) {
                #pragma unroll
                for (int g = 0; g < 4; ++g)
                    bn[g] = ((const s16x8*)P1)[((g * 32 + c) * 16 + ks + 1) * 64 + lane];
            }
            #pragma unroll
            for (int g = 0; g < 4; ++g)
                #pragma unroll
                for (int rt = 0; rt < 8; ++rt)
                    acc[rt][g] = __builtin_amdgcn_mfma_f32_16x16x32_bf16(a[rt], bc[g], acc[rt][g], 0, 0, 0);
            #pragma unroll
            for (int g = 0; g < 4; ++g) bc[g] = bn[g];
        }
        #pragma unroll
        for (int rt = 0; rt < 8; ++rt)
            #pragma unroll
            for (int r = 0; r < 4; ++r) {
                int ml = rt * 16 + lg * 4 + r;
                int m = m0 + ml;
                float iv = sigm(acc[rt][0][r]);
                float fv = sigm(acc[rt][1][r]);
                float gv = tanh_(acc[rt][2][r]);
                float ov = sigm(acc[rt][3][r]);
                size_t o = (size_t)m * HID + nc;
                float cold = c1s[o];
                float cn = fv * cold + iv * gv;
                c1s[o] = cn;
                float hn = ov * tanh_(cn);
                h1s[o] = f2bf(hn);
            }
    }
    __syncthreads();
    __threadfence();   // drain + invalidate L1 so re-read of h1s sees layer-1 writes

    // -------- layer 2: two row-halves of 64, buf = [64][1024] = h1_new | h2_old --------
    #pragma unroll 1
    for (int rh = 0; rh < 2; ++rh) {
        {
            const char* s1 = (const char*)(h1s + (size_t)(m0 + rh * 64) * HID);
            const char* s2 = (const char*)(h2s + (size_t)(m0 + rh * 64) * HID);
            #pragma unroll
            for (int j = 0; j < 16; ++j) {
                int e = tid * 16 + j * 8192;
                int row = e >> 11, colb = e & 2047;
                const char* src = (colb < 1024) ? (s1 + row * 1024 + colb)
                                                : (s2 + row * 1024 + (colb - 1024));
                uint4 v = *(const uint4*)src;
                *(uint4*)((char*)buf + row * 2048 + (colb ^ ((row & 7) << 4))) = v;
            }
        }
        __syncthreads();

        #pragma unroll 1
        for (int cc = 0; cc < 4; ++cc) {
            int c = wave * 4 + cc;
            int nc = c * 16 + l15;
            f32x4 acc[4][4];
            #pragma unroll
            for (int g = 0; g < 4; ++g) {
                float bgv = b2[g * 512 + nc];
                #pragma unroll
                for (int rt = 0; rt < 4; ++rt)
                    #pragma unroll
                    for (int r = 0; r < 4; ++r)
                        acc[rt][g][r] = bgv;
            }
            s16x8 bc[4], bn[4];
            #pragma unroll
            for (int g = 0; g < 4; ++g)
                bc[g] = ((const s16x8*)P2)[((g * 32 + c) * 32 + 0) * 64 + lane];
            #pragma unroll
            for (int ks = 0; ks < 32; ++ks) {
                s16x8 a[4];
                #pragma unroll
                for (int rt = 0; rt < 4; ++rt) {
                    int ao = (rt * 16 + l15) * 2048 + ((ks * 64 + lg * 16) ^ swz);
                    a[rt] = *(const s16x8*)((const char*)buf + ao);
                }
                if (ks < 31) {
                    #pragma unroll
                    for (int g = 0; g < 4; ++g)
                        bn[g] = ((const s16x8*)P2)[((g * 32 + c) * 32 + ks + 1) * 64 + lane];
                }
                #pragma unroll
                for (int g = 0; g < 4; ++g)
                    #pragma unroll
                    for (int rt = 0; rt < 4; ++rt)
                        acc[rt][g] = __builtin_amdgcn_mfma_f32_16x16x32_bf16(a[rt], bc[g], acc[rt][g], 0, 0, 0);
                #pragma unroll
                for (int g = 0; g < 4; ++g) bc[g] = bn[g];
            }
            float wo0 = w_out[nc], wo1 = w_out[512 + nc];
            #pragma unroll
            for (int rt = 0; rt < 4; ++rt)
                #pragma unroll
                for (int r = 0; r < 4; ++r) {
                    int ml = rh * 64 + rt * 16 + lg * 4 + r;
                    int m = m0 + ml;
                    float iv = sigm(acc[rt][0][r]);
                    float fv = sigm(acc[rt][1][r]);
                    float gv = tanh_(acc[rt][2][r]);
                    float ov = sigm(acc[rt][3][r]);
                    size_t o = (size_t)m * HID + nc;
                    float cold = c2s[o];
                    float cn = fv * cold + iv * gv;
                    c2s[o] = cn;
                    float hn = ov * tanh_(cn);
                    h2s[o] = f2bf(hn);
                    float p0 = hn * wo0, p1 = hn * wo1;
                    #pragma unroll
                    for (int s = 1; s < 16; s <<= 1) {
                        p0 += __shfl_xor(p0, s, 64);
                        p1 += __shfl_xor(p1, s, 64);
                    }
                    if (l15 == 0) {
                        atomicAdd(&pls[ml * 2 + 0], p0);
                        atomicAdd(&pls[ml * 2 + 1], p1);
                    }
                }
        }
        __syncthreads();
    }

    if (tid < 2 * BM) {
        int ml = tid >> 1, j = tid & 1;
        float p = pls[tid] + b_out[j];
        out[(size_t)(m0 + ml) * (2 * NSTEP) + t * 2 + j] = p;
        xs[m0 * 2 + tid] = p;
    }
}

extern "C" void kernel_launch(void* const* d_in, const int* in_sizes, int n_in,
                              void* d_out, int out_size, void* d_ws, size_t ws_size,
                              hipStream_t stream)
{
    (void)in_sizes; (void)n_in; (void)out_size; (void)ws_size;
    const float* h        = (const float*)d_in[0];
    const float* w_init_h = (const float*)d_in[1];
    const float* b_init_h = (const float*)d_in[2];
    const float* w_init_c = (const float*)d_in[3];
    const float* b_init_c = (const float*)d_in[4];
    const float* w_ih0    = (const float*)d_in[5];
    const float* w_hh0    = (const float*)d_in[6];
    const float* b_ih0    = (const float*)d_in[7];
    const float* b_hh0    = (const float*)d_in[8];
    const float* w_ih1    = (const float*)d_in[9];
    const float* w_hh1    = (const float*)d_in[10];
    const float* b_ih1    = (const float*)d_in[11];
    const float* b_hh1    = (const float*)d_in[12];
    const float* w_out    = (const float*)d_in[13];
    const float* b_out    = (const float*)d_in[14];
    float* out = (float*)d_out;

    char* ws = (char*)d_ws;
    unsigned short* h1s = (unsigned short*)(ws + 0);
    unsigned short* h2s = (unsigned short*)(ws + 33554432);
    float* c1s          = (float*)(ws + 67108864);
    float* c2s          = (float*)(ws + 134217728);
    float* xs           = (float*)(ws + 201326592);
    unsigned short* P1  = (unsigned short*)(ws + 201588736);
    unsigned short* P2  = (unsigned short*)(ws + 203685888);
    unsigned short* PI  = (unsigned short*)(ws + 207880192);
    float* b1           = (float*)(ws + 208928768);
    float* b2           = (float*)(ws + 208936960);

    pack_kernel<<<14352, 256, 0, stream>>>(w_hh0, w_ih1, w_hh1, w_init_h, w_init_c,
                                           b_ih0, b_hh0, b_ih1, b_hh1, P1, P2, PI, b1, b2);
    init_kernel<<<BATCH / BMI, TPB, 0, stream>>>(h, PI, b_init_h, b_init_c, h1s, h2s, c1s, c2s, xs);
    for (int t = 0; t < NSTEP; ++t)
        step_kernel<<<BATCH / BM, TPB, 0, stream>>>(h1s, h2s, c1s, c2s, xs, P1, P2, b1, b2,
                                                    w_ih0, w_out, b_out, out, t);
}

// Round 3
// 39916.525 us; speedup vs baseline: 3.0397x; 3.0010x over previous
//
#include <hip/hip_runtime.h>

#define HID    512
#define TPB    512
#define NSTEP  60
#define BMI    64

using f32x4 = __attribute__((ext_vector_type(4))) float;
using s16x8 = __attribute__((ext_vector_type(8))) short;

__device__ __forceinline__ unsigned short f2bf(float f) {
    unsigned u = __builtin_bit_cast(unsigned, f);
    u += 0x7fffu + ((u >> 16) & 1u);
    return (unsigned short)(u >> 16);
}
__device__ __forceinline__ float bf2f(unsigned u) {
    return __builtin_bit_cast(float, u << 16);
}
__device__ __forceinline__ float sigm(float x) { return 1.0f / (1.0f + __expf(-x)); }
__device__ __forceinline__ float tanh_(float x) { return 1.0f - 2.0f / (__expf(2.0f * x) + 1.0f); }

// ---------------- weight packing ----------------
// PW1: per (slice s, ct=wave, ks): B-frag [lane][8] for w_hh0; local col cl=ct*16+(lane&15),
//      gate g=cl>>5, jj=cl&31, gcol=g*512+s*32+jj, k=ks*32+(lane>>4)*8+e.  1,048,576 bf16.
// PW2: same for [w_ih1 (ks<16) | w_hh1 (ks>=16)], 32 ks. 2,097,152 bf16.
// PI : init-kernel packing (unchanged from r1). 524,288 bf16.
// b1 = b_ih0+b_hh0 ; b2 = b_ih1+b_hh1
__global__ void pack_kernel(const float* __restrict__ w_hh0, const float* __restrict__ w_ih1,
                            const float* __restrict__ w_hh1, const float* __restrict__ w_init_h,
                            const float* __restrict__ w_init_c,
                            const float* __restrict__ b_ih0, const float* __restrict__ b_hh0,
                            const float* __restrict__ b_ih1, const float* __restrict__ b_hh1,
                            unsigned short* __restrict__ PW1, unsigned short* __restrict__ PW2,
                            unsigned short* __restrict__ PI,
                            float* __restrict__ b1, float* __restrict__ b2)
{
    int idx = blockIdx.x * 256 + threadIdx.x;
    if (idx < 1048576) {
        int el = idx & 511, fr = idx >> 9;
        int ks = fr & 15, ct = (fr >> 4) & 7, s = fr >> 7;
        int lane = el >> 3, e = el & 7;
        int cl = ct * 16 + (lane & 15);
        int gcol = (cl >> 5) * 512 + s * 32 + (cl & 31);
        int k = ks * 32 + (lane >> 4) * 8 + e;
        PW1[idx] = f2bf(w_hh0[gcol * 512 + k]);
        return;
    }
    int i2 = idx - 1048576;
    if (i2 >= 0 && i2 < 2097152) {
        int el = i2 & 511, fr = i2 >> 9;
        int ks = fr & 31, ct = (fr >> 5) & 7, s = fr >> 8;
        int lane = el >> 3, e = el & 7;
        int cl = ct * 16 + (lane & 15);
        int gcol = (cl >> 5) * 512 + s * 32 + (cl & 31);
        int kk = (ks & 15) * 32 + (lane >> 4) * 8 + e;
        float v = (ks < 16) ? w_ih1[gcol * 512 + kk] : w_hh1[gcol * 512 + kk];
        PW2[i2] = f2bf(v);
        return;
    }
    int i3 = idx - (1048576 + 2097152);
    if (i3 >= 0 && i3 < 524288) {
        int el = i3 & 511, fr = i3 >> 9;
        int ks = fr & 15, tile = fr >> 4;
        int s = tile >> 5, c = tile & 31;
        int lane = el >> 3, e = el & 7;
        int n = c * 16 + (lane & 15);
        int k = ks * 32 + (lane >> 4) * 8 + e;
        float v = s ? w_init_c[n * 512 + k] : w_init_h[n * 512 + k];
        PI[i3] = f2bf(v);
        return;
    }
    int i4 = idx - (1048576 + 2097152 + 524288);
    if (i4 >= 0 && i4 < 2048) b1[i4] = b_ih0[i4] + b_hh0[i4];
    else if (i4 >= 2048 && i4 < 4096) b2[i4 - 2048] = b_ih1[i4 - 2048] + b_hh1[i4 - 2048];
}

// ---------------- init: h0/c0 from input h; writes into ping-pong slot 1; c in bf16 ----------------
__global__ __launch_bounds__(TPB, 2) void init_kernel(
    const float* __restrict__ hin, const unsigned short* __restrict__ PI,
    const float* __restrict__ b_init_h, const float* __restrict__ b_init_c,
    unsigned short* __restrict__ h1s, unsigned short* __restrict__ h2s,
    unsigned short* __restrict__ c1s, unsigned short* __restrict__ c2s,
    float* __restrict__ xs0, float* __restrict__ xs1)
{
    __shared__ unsigned short bufA[BMI * HID];
    const int tid = threadIdx.x, lane = tid & 63, wave = tid >> 6;
    const int m0 = blockIdx.x * BMI;
    const int l15 = lane & 15, lg = lane >> 4;
    const int swz = (lane & 7) << 4;

    for (int j = 0; j < 16; ++j) {
        int e = tid * 4 + j * 2048;
        int row = e >> 9, col = e & 511;
        float4 v = *(const float4*)(hin + (size_t)(m0 + row) * HID + col);
        ushort4 w;
        w.x = f2bf(v.x); w.y = f2bf(v.y); w.z = f2bf(v.z); w.w = f2bf(v.w);
        int L = (row * 1024 + col * 2) ^ ((row & 7) << 4);
        *(ushort4*)((char*)bufA + L) = w;
    }
    if (tid < 2 * BMI) { xs0[m0 * 2 + tid] = 0.0f; xs1[m0 * 2 + tid] = 0.0f; }
    __syncthreads();

    #pragma unroll 1
    for (int cc = 0; cc < 4; ++cc) {
        int c = wave * 4 + cc;
        int nc = c * 16 + l15;
        f32x4 acc[4][2];
        #pragma unroll
        for (int rt = 0; rt < 4; ++rt)
            #pragma unroll
            for (int s = 0; s < 2; ++s)
                #pragma unroll
                for (int r = 0; r < 4; ++r) acc[rt][s][r] = 0.0f;

        #pragma unroll
        for (int ks = 0; ks < 16; ++ks) {
            s16x8 a[4];
            #pragma unroll
            for (int rt = 0; rt < 4; ++rt) {
                int ao = (rt * 16 + l15) * 1024 + ((ks * 64 + lg * 16) ^ swz);
                a[rt] = *(const s16x8*)((const char*)bufA + ao);
            }
            #pragma unroll
            for (int s = 0; s < 2; ++s) {
                s16x8 b = ((const s16x8*)PI)[((s * 32 + c) * 16 + ks) * 64 + lane];
                #pragma unroll
                for (int rt = 0; rt < 4; ++rt)
                    acc[rt][s] = __builtin_amdgcn_mfma_f32_16x16x32_bf16(a[rt], b, acc[rt][s], 0, 0, 0);
            }
        }
        float bh = b_init_h[nc], bc = b_init_c[nc];
        #pragma unroll
        for (int rt = 0; rt < 4; ++rt)
            #pragma unroll
            for (int r = 0; r < 4; ++r) {
                int m = m0 + rt * 16 + lg * 4 + r;
                float hv = acc[rt][0][r] + bh;
                float cv = acc[rt][1][r] + bc;
                unsigned short hb = f2bf(hv);
                size_t o = (size_t)m * HID + nc;
                h1s[o] = hb; h2s[o] = hb;
                c1s[o] = f2bf(cv); c2s[o] = f2bf(cv);
            }
    }
}

// ---------------- layer-1 phase kernel ----------------
// block b -> group g (XCD-local via b%8), slice s. 2048 rows x 32 hidden units.
// B-frags (w_hh0 slice) in registers; A (h1_old) chunk-staged in LDS, shared by 8 waves.
__global__ __launch_bounds__(TPB, 2) void l1_kernel(
    const unsigned short* __restrict__ h1R, unsigned short* __restrict__ h1W,
    unsigned short* __restrict__ c1s,
    const float* __restrict__ xsR, float* __restrict__ xsW,
    float* __restrict__ outp,
    const unsigned short* __restrict__ PW1, const float* __restrict__ b1,
    const float* __restrict__ w_ih0, const float* __restrict__ b_out, int t)
{
    __shared__ __align__(16) unsigned short Ab[32 * HID];   // 32 KB
    __shared__ __align__(16) float gl[32 * 128];            // 16 KB gate buffer
    const int tid = threadIdx.x, lane = tid & 63, w = tid >> 6;
    const int b = blockIdx.x;
    const int g = 2 * (b & 7) + (b >> 7);
    const int s = (b >> 3) & 15;
    const int m0 = g * 2048;
    const int l15 = lane & 15, lg = lane >> 4;

    // zero next-x accumulator for this group's rows (used by this step's L2 atomics)
    for (int i = tid; i < 2048; i += TPB)
        *(float2*)(xsW + (size_t)(m0 + i) * 2) = make_float2(0.f, 0.f);

    // write out[:, t-1] (one slice per group does it)
    if (t > 0 && s == 0) {
        float a0 = b_out[0], a1 = b_out[1];
        for (int i = tid; i < 2048; i += TPB) {
            float2 v = *(const float2*)(xsR + (size_t)(m0 + i) * 2);
            float* op = outp + (size_t)(m0 + i) * (2 * NSTEP) + (t - 1) * 2;
            op[0] = v.x + a0; op[1] = v.y + a1;
        }
    }

    // B fragments -> registers (64 VGPR)
    s16x8 bw[16];
    #pragma unroll
    for (int ks = 0; ks < 16; ++ks)
        bw[ks] = ((const s16x8*)PW1)[((s * 8 + w) * 16 + ks) * 64 + lane];

    // epilogue role + constants: thread -> (erow, 2 hidden units)
    const int erow = tid >> 4, ejp = tid & 15;
    float b1v[8], wiA[8], wiB[8];
    #pragma unroll
    for (int q = 0; q < 8; ++q) {
        int dj = q & 1, gq = q >> 1;
        int gcol = gq * 512 + s * 32 + ejp * 2 + dj;
        b1v[q] = b1[gcol];
        wiA[q] = w_ih0[gcol * 2 + 0];
        wiB[q] = w_ih0[gcol * 2 + 1];
    }
    float bo0 = b_out[0], bo1 = b_out[1];

    const char* srcBase = (const char*)h1R + (size_t)m0 * (HID * 2);

    // prologue: stage chunk 0 (reg->LDS, XOR-swizzled rows)
    uint4 nv[4];
    #pragma unroll
    for (int p = 0; p < 4; ++p)
        nv[p] = *(const uint4*)(srcBase + p * 8192 + tid * 16);
    #pragma unroll
    for (int p = 0; p < 4; ++p) {
        int off = p * 8192 + tid * 16;
        int row = off >> 10, colb = off & 1023;
        *(uint4*)((char*)Ab + row * 1024 + (colb ^ ((row & 7) << 4))) = nv[p];
    }

    #pragma unroll 1
    for (int ch = 0; ch < 64; ++ch) {
        __syncthreads();   // Ab[ch] visible; previous epilogue done with gl

        if (ch < 63) {     // prefetch next chunk into registers (latency hides under MFMA)
            const char* src = srcBase + (size_t)(ch + 1) * 32768;
            #pragma unroll
            for (int p = 0; p < 4; ++p)
                nv[p] = *(const uint4*)(src + p * 8192 + tid * 16);
        }

        // GEMM: 32 rows x 16 cols (col = w*16+l15), K=512
        f32x4 acc0 = {0.f, 0.f, 0.f, 0.f}, acc1 = {0.f, 0.f, 0.f, 0.f};
        #pragma unroll
        for (int ks = 0; ks < 16; ++ks) {
            int kb = (ks * 64 + lg * 16);
            s16x8 a0 = *(const s16x8*)((const char*)Ab + l15 * 1024 + (kb ^ ((l15 & 7) << 4)));
            s16x8 a1 = *(const s16x8*)((const char*)Ab + (l15 + 16) * 1024 + (kb ^ ((l15 & 7) << 4)));
            acc0 = __builtin_amdgcn_mfma_f32_16x16x32_bf16(a0, bw[ks], acc0, 0, 0, 0);
            acc1 = __builtin_amdgcn_mfma_f32_16x16x32_bf16(a1, bw[ks], acc1, 0, 0, 0);
        }
        {   // gates -> LDS:  gl[row][jl][gate]
            int col = w * 16 + l15;
            int base = (col & 31) * 4 + (col >> 5);
            #pragma unroll
            for (int r = 0; r < 4; ++r) {
                gl[(lg * 4 + r) * 128 + base] = acc0[r];
                gl[(16 + lg * 4 + r) * 128 + base] = acc1[r];
            }
        }
        __syncthreads();   // Ab reads done; gl complete

        if (ch < 63) {     // write prefetched chunk into Ab
            #pragma unroll
            for (int p = 0; p < 4; ++p) {
                int off = p * 8192 + tid * 16;
                int row = off >> 10, colb = off & 1023;
                *(uint4*)((char*)Ab + row * 1024 + (colb ^ ((row & 7) << 4))) = nv[p];
            }
        }

        // epilogue: nonlinearity + c1 update + h1 write (2 hidden units / thread)
        {
            int m = m0 + ch * 32 + erow;
            float x0 = 0.f, x1 = 0.f;
            if (t > 0) {
                float2 xv = *(const float2*)(xsR + (size_t)m * 2);
                x0 = xv.x + bo0; x1 = xv.y + bo1;
            }
            f32x4 ga = *(const f32x4*)(gl + erow * 128 + ejp * 8);
            f32x4 gb = *(const f32x4*)(gl + erow * 128 + ejp * 8 + 4);
            int cix = m * HID + s * 32 + ejp * 2;
            unsigned cp = *(const unsigned*)(c1s + cix);
            float cold0 = bf2f(cp & 0xffffu), cold1 = bf2f(cp >> 16);
            float i0 = sigm(ga[0] + b1v[0] + x0 * wiA[0] + x1 * wiB[0]);
            float f0 = sigm(ga[1] + b1v[2] + x0 * wiA[2] + x1 * wiB[2]);
            float g0 = tanh_(ga[2] + b1v[4] + x0 * wiA[4] + x1 * wiB[4]);
            float o0 = sigm(ga[3] + b1v[6] + x0 * wiA[6] + x1 * wiB[6]);
            float cn0 = f0 * cold0 + i0 * g0;
            float hn0 = o0 * tanh_(cn0);
            float i1 = sigm(gb[0] + b1v[1] + x0 * wiA[1] + x1 * wiB[1]);
            float f1 = sigm(gb[1] + b1v[3] + x0 * wiA[3] + x1 * wiB[3]);
            float g1 = tanh_(gb[2] + b1v[5] + x0 * wiA[5] + x1 * wiB[5]);
            float o1 = sigm(gb[3] + b1v[7] + x0 * wiA[7] + x1 * wiB[7]);
            float cn1 = f1 * cold1 + i1 * g1;
            float hn1 = o1 * tanh_(cn1);
            *(unsigned*)(c1s + cix) = (unsigned)f2bf(cn0) | ((unsigned)f2bf(cn1) << 16);
            *(unsigned*)(h1W + cix) = (unsigned)f2bf(hn0) | ((unsigned)f2bf(hn1) << 16);
        }
    }
}

// ---------------- layer-2 phase kernel ----------------
// A = [h1_new | h2_old], K=1024; B-frags (w_ih1|w_hh1 slice) in registers (128 VGPR).
__global__ __launch_bounds__(TPB, 2) void l2_kernel(
    const unsigned short* __restrict__ h1C, const unsigned short* __restrict__ h2R,
    unsigned short* __restrict__ h2W, unsigned short* __restrict__ c2s,
    float* __restrict__ xsW,
    const unsigned short* __restrict__ PW2, const float* __restrict__ b2,
    const float* __restrict__ w_out)
{
    __shared__ __align__(16) unsigned short Ab[32 * 1024];  // 64 KB
    __shared__ __align__(16) float gl[32 * 128];            // 16 KB
    const int tid = threadIdx.x, lane = tid & 63, w = tid >> 6;
    const int b = blockIdx.x;
    const int g = 2 * (b & 7) + (b >> 7);
    const int s = (b >> 3) & 15;
    const int m0 = g * 2048;
    const int l15 = lane & 15, lg = lane >> 4;

    s16x8 bw[32];
    #pragma unroll
    for (int ks = 0; ks < 32; ++ks)
        bw[ks] = ((const s16x8*)PW2)[((s * 8 + w) * 32 + ks) * 64 + lane];

    const int erow = tid >> 4, ejp = tid & 15;
    float b2v[8];
    #pragma unroll
    for (int q = 0; q < 8; ++q) {
        int dj = q & 1, gq = q >> 1;
        b2v[q] = b2[gq * 512 + s * 32 + ejp * 2 + dj];
    }
    float woA0 = w_out[s * 32 + ejp * 2], woA1 = w_out[s * 32 + ejp * 2 + 1];
    float woB0 = w_out[512 + s * 32 + ejp * 2], woB1 = w_out[512 + s * 32 + ejp * 2 + 1];

    const char* s1 = (const char*)h1C + (size_t)m0 * 1024;
    const char* s2 = (const char*)h2R + (size_t)m0 * 1024;

    uint4 nv[8];
    #pragma unroll
    for (int p = 0; p < 8; ++p) {
        int off = p * 8192 + tid * 16;
        int row = off >> 11, colb = off & 2047;
        nv[p] = (colb < 1024) ? *(const uint4*)(s1 + row * 1024 + colb)
                              : *(const uint4*)(s2 + row * 1024 + (colb - 1024));
    }
    #pragma unroll
    for (int p = 0; p < 8; ++p) {
        int off = p * 8192 + tid * 16;
        int row = off >> 11, colb = off & 2047;
        *(uint4*)((char*)Ab + row * 2048 + (colb ^ ((row & 7) << 4))) = nv[p];
    }

    #pragma unroll 1
    for (int ch = 0; ch < 64; ++ch) {
        __syncthreads();

        if (ch < 63) {
            #pragma unroll
            for (int p = 0; p < 8; ++p) {
                int off = p * 8192 + tid * 16;
                int row = (ch + 1) * 32 + (off >> 11), colb = off & 2047;
                nv[p] = (colb < 1024) ? *(const uint4*)(s1 + (size_t)row * 1024 + colb)
                                      : *(const uint4*)(s2 + (size_t)row * 1024 + (colb - 1024));
            }
        }

        f32x4 acc0 = {0.f, 0.f, 0.f, 0.f}, acc1 = {0.f, 0.f, 0.f, 0.f};
        #pragma unroll
        for (int ks = 0; ks < 32; ++ks) {
            int kb = (ks * 64 + lg * 16);
            s16x8 a0 = *(const s16x8*)((const char*)Ab + l15 * 2048 + (kb ^ ((l15 & 7) << 4)));
            s16x8 a1 = *(const s16x8*)((const char*)Ab + (l15 + 16) * 2048 + (kb ^ ((l15 & 7) << 4)));
            acc0 = __builtin_amdgcn_mfma_f32_16x16x32_bf16(a0, bw[ks], acc0, 0, 0, 0);
            acc1 = __builtin_amdgcn_mfma_f32_16x16x32_bf16(a1, bw[ks], acc1, 0, 0, 0);
        }
        {
            int col = w * 16 + l15;
            int base = (col & 31) * 4 + (col >> 5);
            #pragma unroll
            for (int r = 0; r < 4; ++r) {
                gl[(lg * 4 + r) * 128 + base] = acc0[r];
                gl[(16 + lg * 4 + r) * 128 + base] = acc1[r];
            }
        }
        __syncthreads();

        if (ch < 63) {
            #pragma unroll
            for (int p = 0; p < 8; ++p) {
                int off = p * 8192 + tid * 16;
                int row = off >> 11, colb = off & 2047;
                *(uint4*)((char*)Ab + row * 2048 + (colb ^ ((row & 7) << 4))) = nv[p];
            }
        }

        {
            int m = m0 + ch * 32 + erow;
            f32x4 ga = *(const f32x4*)(gl + erow * 128 + ejp * 8);
            f32x4 gb = *(const f32x4*)(gl + erow * 128 + ejp * 8 + 4);
            int cix = m * HID + s * 32 + ejp * 2;
            unsigned cp = *(const unsigned*)(c2s + cix);
            float cold0 = bf2f(cp & 0xffffu), cold1 = bf2f(cp >> 16);
            float i0 = sigm(ga[0] + b2v[0]);
            float f0 = sigm(ga[1] + b2v[2]);
            float g0 = tanh_(ga[2] + b2v[4]);
            float o0 = sigm(ga[3] + b2v[6]);
            float cn0 = f0 * cold0 + i0 * g0;
            float hn0 = o0 * tanh_(cn0);
            float i1 = sigm(gb[0] + b2v[1]);
            float f1 = sigm(gb[1] + b2v[3]);
            float g1 = tanh_(gb[2] + b2v[5]);
            float o1 = sigm(gb[3] + b2v[7]);
            float cn1 = f1 * cold1 + i1 * g1;
            float hn1 = o1 * tanh_(cn1);
            *(unsigned*)(c2s + cix) = (unsigned)f2bf(cn0) | ((unsigned)f2bf(cn1) << 16);
            *(unsigned*)(h2W + cix) = (unsigned)f2bf(hn0) | ((unsigned)f2bf(hn1) << 16);
            // output-projection partials: reduce over the 16 ejp lanes of this row
            float p0 = hn0 * woA0 + hn1 * woA1;
            float p1 = hn0 * woB0 + hn1 * woB1;
            #pragma unroll
            for (int d = 1; d < 16; d <<= 1) {
                p0 += __shfl_xor(p0, d, 16);
                p1 += __shfl_xor(p1, d, 16);
            }
            if (ejp == 0) {
                atomicAdd(xsW + (size_t)m * 2, p0);
                atomicAdd(xsW + (size_t)m * 2 + 1, p1);
            }
        }
    }
}

// ---------------- final-step output ----------------
__global__ void tail_kernel(const float* __restrict__ xs0, const float* __restrict__ b_out,
                            float* __restrict__ outp)
{
    int i = blockIdx.x * 256 + threadIdx.x;
    if (i < 65536) {
        int m = i >> 1, j = i & 1;
        outp[(size_t)m * (2 * NSTEP) + (NSTEP - 1) * 2 + j] = xs0[i] + b_out[j];
    }
}

extern "C" void kernel_launch(void* const* d_in, const int* in_sizes, int n_in,
                              void* d_out, int out_size, void* d_ws, size_t ws_size,
                              hipStream_t stream)
{
    (void)in_sizes; (void)n_in; (void)out_size; (void)ws_size;
    const float* h        = (const float*)d_in[0];
    const float* w_init_h = (const float*)d_in[1];
    const float* b_init_h = (const float*)d_in[2];
    const float* w_init_c = (const float*)d_in[3];
    const float* b_init_c = (const float*)d_in[4];
    const float* w_ih0    = (const float*)d_in[5];
    const float* w_hh0    = (const float*)d_in[6];
    const float* b_ih0    = (const float*)d_in[7];
    const float* b_hh0    = (const float*)d_in[8];
    const float* w_ih1    = (const float*)d_in[9];
    const float* w_hh1    = (const float*)d_in[10];
    const float* b_ih1    = (const float*)d_in[11];
    const float* b_hh1    = (const float*)d_in[12];
    const float* w_out    = (const float*)d_in[13];
    const float* b_out    = (const float*)d_in[14];
    float* out = (float*)d_out;

    char* ws = (char*)d_ws;
    unsigned short* h1s[2] = { (unsigned short*)(ws + 0),
                               (unsigned short*)(ws + 33554432) };
    unsigned short* h2s[2] = { (unsigned short*)(ws + 67108864),
                               (unsigned short*)(ws + 100663296) };
    unsigned short* c1s = (unsigned short*)(ws + 134217728);
    unsigned short* c2s = (unsigned short*)(ws + 167772160);
    float* xs[2] = { (float*)(ws + 201326592), (float*)(ws + 201588736) };
    unsigned short* PW1 = (unsigned short*)(ws + 201850880);
    unsigned short* PW2 = (unsigned short*)(ws + 203948032);
    unsigned short* PI  = (unsigned short*)(ws + 208142336);
    float* b1 = (float*)(ws + 209190912);
    float* b2 = (float*)(ws + 209199104);

    pack_kernel<<<14352, 256, 0, stream>>>(w_hh0, w_ih1, w_hh1, w_init_h, w_init_c,
                                           b_ih0, b_hh0, b_ih1, b_hh1, PW1, PW2, PI, b1, b2);
    // init writes ping-pong slot 1 (read at t=0), zeroes both x buffers
    init_kernel<<<32768 / BMI, TPB, 0, stream>>>(h, PI, b_init_h, b_init_c,
                                                 h1s[1], h2s[1], c1s, c2s, xs[0], xs[1]);
    for (int t = 0; t < NSTEP; ++t) {
        const unsigned short* h1R = h1s[(t + 1) & 1];
        unsigned short* h1W = h1s[t & 1];
        const unsigned short* h2R = h2s[(t + 1) & 1];
        unsigned short* h2W = h2s[t & 1];
        const float* xsR = xs[t & 1];
        float* xsW = xs[(t + 1) & 1];
        l1_kernel<<<256, TPB, 0, stream>>>(h1R, h1W, c1s, xsR, xsW, out, PW1, b1,
                                           w_ih0, b_out, t);
        l2_kernel<<<256, TPB, 0, stream>>>(h1W, h2R, h2W, c2s, xsW, PW2, b2, w_out);
    }
    tail_kernel<<<256, 256, 0, stream>>>(xs[0], b_out, out);
}

// Round 4
// 38764.578 us; speedup vs baseline: 3.1301x; 1.0297x over previous
//
#include <hip/hip_runtime.h>

#define HID    512
#define TPB    512
#define NSTEP  60
#define BMI    64

using f32x4 = __attribute__((ext_vector_type(4))) float;
using s16x8 = __attribute__((ext_vector_type(8))) short;

__device__ __forceinline__ unsigned short f2bf(float f) {
    unsigned u = __builtin_bit_cast(unsigned, f);
    u += 0x7fffu + ((u >> 16) & 1u);
    return (unsigned short)(u >> 16);
}
__device__ __forceinline__ float bf2f(unsigned u) {
    return __builtin_bit_cast(float, u << 16);
}
__device__ __forceinline__ float sigm(float x) { return 1.0f / (1.0f + __expf(-x)); }
__device__ __forceinline__ float tanh_(float x) { return 1.0f - 2.0f / (__expf(2.0f * x) + 1.0f); }

// XOR-gate un-permute: pa[g] = q[g ^ lgr], lgr wave-uniform
__device__ __forceinline__ f32x4 deperm(f32x4 q, int lgr) {
    f32x4 p;
    if (lgr == 0)      { p[0]=q[0]; p[1]=q[1]; p[2]=q[2]; p[3]=q[3]; }
    else if (lgr == 1) { p[0]=q[1]; p[1]=q[0]; p[2]=q[3]; p[3]=q[2]; }
    else if (lgr == 2) { p[0]=q[2]; p[1]=q[3]; p[2]=q[0]; p[3]=q[1]; }
    else               { p[0]=q[3]; p[1]=q[2]; p[2]=q[1]; p[3]=q[0]; }
    return p;
}

// ---------------- weight packing (identical to r3 — verified) ----------------
__global__ void pack_kernel(const float* __restrict__ w_hh0, const float* __restrict__ w_ih1,
                            const float* __restrict__ w_hh1, const float* __restrict__ w_init_h,
                            const float* __restrict__ w_init_c,
                            const float* __restrict__ b_ih0, const float* __restrict__ b_hh0,
                            const float* __restrict__ b_ih1, const float* __restrict__ b_hh1,
                            unsigned short* __restrict__ PW1, unsigned short* __restrict__ PW2,
                            unsigned short* __restrict__ PI,
                            float* __restrict__ b1, float* __restrict__ b2)
{
    int idx = blockIdx.x * 256 + threadIdx.x;
    if (idx < 1048576) {
        int el = idx & 511, fr = idx >> 9;
        int ks = fr & 15, ct = (fr >> 4) & 7, s = fr >> 7;
        int lane = el >> 3, e = el & 7;
        int cl = ct * 16 + (lane & 15);
        int gcol = (cl >> 5) * 512 + s * 32 + (cl & 31);
        int k = ks * 32 + (lane >> 4) * 8 + e;
        PW1[idx] = f2bf(w_hh0[gcol * 512 + k]);
        return;
    }
    int i2 = idx - 1048576;
    if (i2 >= 0 && i2 < 2097152) {
        int el = i2 & 511, fr = i2 >> 9;
        int ks = fr & 31, ct = (fr >> 5) & 7, s = fr >> 8;
        int lane = el >> 3, e = el & 7;
        int cl = ct * 16 + (lane & 15);
        int gcol = (cl >> 5) * 512 + s * 32 + (cl & 31);
        int kk = (ks & 15) * 32 + (lane >> 4) * 8 + e;
        float v = (ks < 16) ? w_ih1[gcol * 512 + kk] : w_hh1[gcol * 512 + kk];
        PW2[i2] = f2bf(v);
        return;
    }
    int i3 = idx - (1048576 + 2097152);
    if (i3 >= 0 && i3 < 524288) {
        int el = i3 & 511, fr = i3 >> 9;
        int ks = fr & 15, tile = fr >> 4;
        int s = tile >> 5, c = tile & 31;
        int lane = el >> 3, e = el & 7;
        int n = c * 16 + (lane & 15);
        int k = ks * 32 + (lane >> 4) * 8 + e;
        float v = s ? w_init_c[n * 512 + k] : w_init_h[n * 512 + k];
        PI[i3] = f2bf(v);
        return;
    }
    int i4 = idx - (1048576 + 2097152 + 524288);
    if (i4 >= 0 && i4 < 2048) b1[i4] = b_ih0[i4] + b_hh0[i4];
    else if (i4 >= 2048 && i4 < 4096) b2[i4 - 2048] = b_ih1[i4 - 2048] + b_hh1[i4 - 2048];
}

// ---------------- init (r3 structure, xs removed) ----------------
__global__ __launch_bounds__(TPB, 2) void init_kernel(
    const float* __restrict__ hin, const unsigned short* __restrict__ PI,
    const float* __restrict__ b_init_h, const float* __restrict__ b_init_c,
    unsigned short* __restrict__ h1s, unsigned short* __restrict__ h2s,
    unsigned short* __restrict__ c1s, unsigned short* __restrict__ c2s)
{
    __shared__ unsigned short bufA[BMI * HID];
    const int tid = threadIdx.x, lane = tid & 63, wave = tid >> 6;
    const int m0 = blockIdx.x * BMI;
    const int l15 = lane & 15, lg = lane >> 4;
    const int swz = (lane & 7) << 4;

    for (int j = 0; j < 16; ++j) {
        int e = tid * 4 + j * 2048;
        int row = e >> 9, col = e & 511;
        float4 v = *(const float4*)(hin + (size_t)(m0 + row) * HID + col);
        ushort4 w;
        w.x = f2bf(v.x); w.y = f2bf(v.y); w.z = f2bf(v.z); w.w = f2bf(v.w);
        int L = (row * 1024 + col * 2) ^ ((row & 7) << 4);
        *(ushort4*)((char*)bufA + L) = w;
    }
    __syncthreads();

    #pragma unroll 1
    for (int cc = 0; cc < 4; ++cc) {
        int c = wave * 4 + cc;
        int nc = c * 16 + l15;
        f32x4 acc[4][2];
        #pragma unroll
        for (int rt = 0; rt < 4; ++rt)
            #pragma unroll
            for (int s = 0; s < 2; ++s)
                #pragma unroll
                for (int r = 0; r < 4; ++r) acc[rt][s][r] = 0.0f;

        #pragma unroll
        for (int ks = 0; ks < 16; ++ks) {
            s16x8 a[4];
            #pragma unroll
            for (int rt = 0; rt < 4; ++rt) {
                int ao = (rt * 16 + l15) * 1024 + ((ks * 64 + lg * 16) ^ swz);
                a[rt] = *(const s16x8*)((const char*)bufA + ao);
            }
            #pragma unroll
            for (int s = 0; s < 2; ++s) {
                s16x8 b = ((const s16x8*)PI)[((s * 32 + c) * 16 + ks) * 64 + lane];
                #pragma unroll
                for (int rt = 0; rt < 4; ++rt)
                    acc[rt][s] = __builtin_amdgcn_mfma_f32_16x16x32_bf16(a[rt], b, acc[rt][s], 0, 0, 0);
            }
        }
        float bh = b_init_h[nc], bc = b_init_c[nc];
        #pragma unroll
        for (int rt = 0; rt < 4; ++rt)
            #pragma unroll
            for (int r = 0; r < 4; ++r) {
                int m = m0 + rt * 16 + lg * 4 + r;
                float hv = acc[rt][0][r] + bh;
                float cv = acc[rt][1][r] + bc;
                unsigned short hb = f2bf(hv);
                size_t o = (size_t)m * HID + nc;
                h1s[o] = hb; h2s[o] = hb;
                c1s[o] = f2bf(cv); c2s[o] = f2bf(cv);
            }
    }
}

// ---------------- layer-1: gates1 = h1@w_hh0^T + x@w_ih0^T + b1 ----------------
// 8 waves = 2 colG (cg) x 2 Ksplit (kh) x 2 rowSplit (rha). chunk = 32 rows.
// LDS A layout [ks16][rh2][lg4][l15 16][16B] -> all ds ops lane-linear.
__global__ __launch_bounds__(TPB, 2) void l1_kernel(
    const unsigned short* __restrict__ h1R, unsigned short* __restrict__ h1W,
    unsigned short* __restrict__ c1s, const float* __restrict__ pp,
    float* __restrict__ outp, const unsigned short* __restrict__ PW1,
    const float* __restrict__ b1, const float* __restrict__ w_ih0,
    const float* __restrict__ b_out, int t)
{
    __shared__ __align__(16) unsigned short Ab[16384];     // 32 KB
    __shared__ __align__(16) float gl[2][2][2048];         // 32 KB (copy=kh, par=u&1)
    __shared__ __align__(16) float xls[5120];              // 20 KB (4096 used)

    const int tid = threadIdx.x, lane = tid & 63, w = tid >> 6;
    const int b = blockIdx.x;
    const int g = 2 * (b & 7) + (b >> 7);
    const int s = (b >> 3) & 15;
    const int m0 = g * 2048;
    const int l15 = lane & 15, lg = lane >> 4;
    const int cg = w & 1, kh = (w >> 1) & 1, rha = w >> 2;

    // B fragments: ct = cg*4+j, ks = kh*8+ksl  (32 frags, live in AGPRs)
    s16x8 bw[4][8];
    #pragma unroll
    for (int j = 0; j < 4; ++j)
        #pragma unroll
        for (int ksl = 0; ksl < 8; ++ksl)
            bw[j][ksl] = ((const s16x8*)PW1)[(((s * 8 + cg * 4 + j) * 16) + kh * 8 + ksl) * 64 + lane];

    // epilogue constants: row = tid>>4, units ejp*2, ejp*2+1
    const int erow = tid >> 4, ejp = tid & 15;
    const int lgr = w & 3;  // (erow>>2)&3 is wave-uniform == w&3
    float b1v[8], wiA[8], wiB[8];
    #pragma unroll
    for (int q = 0; q < 8; ++q) {
        int dj = q & 1, gq = q >> 1;
        int gcol = gq * 512 + s * 32 + ejp * 2 + dj;
        b1v[q] = b1[gcol];
        wiA[q] = w_ih0[gcol * 2 + 0];
        wiB[q] = w_ih0[gcol * 2 + 1];
    }
    float bo0 = b_out[0], bo1 = b_out[1];

    // ---- reduce prev-step partials -> xls (pred incl. bias); write out[:,t-1] ----
    if (t == 0) {
        #pragma unroll
        for (int i = 0; i < 8; ++i) xls[tid * 8 + i] = 0.0f;
    } else {
        f32x4 s0 = {0.f,0.f,0.f,0.f}, s1 = {0.f,0.f,0.f,0.f};
        #pragma unroll 1
        for (int ss = 0; ss < 16; ++ss) {
            const float* p = pp + (((size_t)(g * 16 + ss)) << 12) + tid * 8;
            s0 += *(const f32x4*)p;
            s1 += *(const f32x4*)(p + 4);
        }
        s0[0] += bo0; s0[1] += bo1; s0[2] += bo0; s0[3] += bo1;
        s1[0] += bo0; s1[1] += bo1; s1[2] += bo0; s1[3] += bo1;
        *(f32x4*)(xls + tid * 8) = s0;
        *(f32x4*)(xls + tid * 8 + 4) = s1;
        if (s == 0) {
            float* ob = outp + (size_t)(m0 + tid * 4) * (2 * NSTEP) + (t - 1) * 2;
            *(float2*)(ob)                 = make_float2(s0[0], s0[1]);
            *(float2*)(ob + 2 * NSTEP)     = make_float2(s0[2], s0[3]);
            *(float2*)(ob + 4 * NSTEP)     = make_float2(s1[0], s1[1]);
            *(float2*)(ob + 6 * NSTEP)     = make_float2(s1[2], s1[3]);
        }
    }

    // staging decompose: LDS addr = p*8192 + tid*16
    const int sl15 = tid & 15, slg = (tid >> 4) & 3, srh = (tid >> 6) & 1, skq = tid >> 7;
    const int sgrow = srh * 16 + sl15;            // chunk-local row
    const int scol  = (tid & 15) * 0;             // (unused)
    (void)scol;

    // prologue: stage chunk 0
    uint4 nv[4];
    #pragma unroll
    for (int p = 0; p < 4; ++p) {
        int ks = p * 4 + skq;
        nv[p] = *(const uint4*)(h1R + (size_t)(m0 + sgrow) * HID + ks * 32 + slg * 8);
    }
    #pragma unroll
    for (int p = 0; p < 4; ++p)
        *(uint4*)((char*)Ab + p * 8192 + tid * 16) = nv[p];

    #pragma unroll 1
    for (int ch = 0; ch < 64; ++ch) {
        __syncthreads();   // (a) Ab + xls ready; prev epilogue done with gl

        if (ch < 63) {     // prefetch chunk ch+1 into registers
            #pragma unroll
            for (int p = 0; p < 4; ++p) {
                int ks = p * 4 + skq;
                nv[p] = *(const uint4*)(h1R + (size_t)(m0 + (ch + 1) * 32 + sgrow) * HID + ks * 32 + slg * 8);
            }
        }

        // K-loop: rows rha*16.., cols (cg*4+j)*16.., K-half kh
        f32x4 acc[4];
        #pragma unroll
        for (int j = 0; j < 4; ++j) { acc[j][0]=0.f; acc[j][1]=0.f; acc[j][2]=0.f; acc[j][3]=0.f; }
        #pragma unroll
        for (int ksl = 0; ksl < 8; ++ksl) {
            int ks = kh * 8 + ksl;
            s16x8 a = *(const s16x8*)((const char*)Ab + ks * 2048 + rha * 1024 + lane * 16);
            #pragma unroll
            for (int j = 0; j < 4; ++j)
                acc[j] = __builtin_amdgcn_mfma_f32_16x16x32_bf16(a, bw[j][ksl], acc[j], 0, 0, 0);
        }
        // gl write (copy kh): par = u&1, idx = row*64 + (u>>1)*4 + (gate^lg)
        #pragma unroll
        for (int j = 0; j < 4; ++j) {
            int col = (cg * 4 + j) * 16 + l15;
            int u = col & 31, gate = col >> 5;
            float* dst = &gl[kh][u & 1][(u >> 1) * 4 + (gate ^ lg)];
            #pragma unroll
            for (int r = 0; r < 4; ++r)
                dst[(rha * 16 + lg * 4 + r) * 64] = acc[j][r];
        }
        __syncthreads();   // (b) gl complete; Ab reads done

        if (ch < 63) {
            #pragma unroll
            for (int p = 0; p < 4; ++p)
                *(uint4*)((char*)Ab + p * 8192 + tid * 16) = nv[p];
        }

        // epilogue: row erow, units ejp*2 / ejp*2+1
        {
            int grow = ch * 32 + erow;
            int m = m0 + grow;
            float x0 = xls[grow * 2 + 0], x1 = xls[grow * 2 + 1];
            int gbase = erow * 64 + ejp * 4;
            f32x4 qa = *(const f32x4*)&gl[0][0][gbase];
            qa += *(const f32x4*)&gl[1][0][gbase];
            f32x4 qb = *(const f32x4*)&gl[0][1][gbase];
            qb += *(const f32x4*)&gl[1][1][gbase];
            qa = deperm(qa, lgr); qb = deperm(qb, lgr);

            int cix = m * HID + s * 32 + ejp * 2;
            unsigned cp = *(const unsigned*)(c1s + cix);
            float cold0 = bf2f(cp & 0xffffu), cold1 = bf2f(cp >> 16);
            float i0 = sigm(qa[0] + b1v[0] + x0 * wiA[0] + x1 * wiB[0]);
            float f0 = sigm(qa[1] + b1v[2] + x0 * wiA[2] + x1 * wiB[2]);
            float g0 = tanh_(qa[2] + b1v[4] + x0 * wiA[4] + x1 * wiB[4]);
            float o0 = sigm(qa[3] + b1v[6] + x0 * wiA[6] + x1 * wiB[6]);
            float cn0 = f0 * cold0 + i0 * g0;
            float hn0 = o0 * tanh_(cn0);
            float i1 = sigm(qb[0] + b1v[1] + x0 * wiA[1] + x1 * wiB[1]);
            float f1 = sigm(qb[1] + b1v[3] + x0 * wiA[3] + x1 * wiB[3]);
            float g1 = tanh_(qb[2] + b1v[5] + x0 * wiA[5] + x1 * wiB[5]);
            float o1 = sigm(qb[3] + b1v[7] + x0 * wiA[7] + x1 * wiB[7]);
            float cn1 = f1 * cold1 + i1 * g1;
            float hn1 = o1 * tanh_(cn1);
            *(unsigned*)(c1s + cix) = (unsigned)f2bf(cn0) | ((unsigned)f2bf(cn1) << 16);
            *(unsigned*)(h1W + cix) = (unsigned)f2bf(hn0) | ((unsigned)f2bf(hn1) << 16);
        }
    }
}

// ---------------- layer-2: gates2 = [h1_new|h2_old]@W2^T + b2 ----------------
// 8 waves = 2 colG (cg) x 4 Ksplit (kq). chunk = 32 rows. K = 1024 (32 frag-ks).
__global__ __launch_bounds__(TPB, 2) void l2_kernel(
    const unsigned short* __restrict__ h1C, const unsigned short* __restrict__ h2R,
    unsigned short* __restrict__ h2W, unsigned short* __restrict__ c2s,
    float* __restrict__ pp,
    const unsigned short* __restrict__ PW2, const float* __restrict__ b2,
    const float* __restrict__ w_out)
{
    __shared__ __align__(16) unsigned short Ab[32768];     // 64 KB
    __shared__ __align__(16) float gl[2][2][2304];         // 36 KB (2048 used/par; pad->1 blk/CU)

    const int tid = threadIdx.x, lane = tid & 63, w = tid >> 6;
    const int b = blockIdx.x;
    const int g = 2 * (b & 7) + (b >> 7);
    const int s = (b >> 3) & 15;
    const int m0 = g * 2048;
    const int l15 = lane & 15, lg = lane >> 4;
    const int cg = w & 1, kq = w >> 1;
    const int copy = kq >> 1, adder = ((kq & 1) == 0);

    // B fragments: ct = cg*4+j, ks = kq*8+ksl (32 frags)
    s16x8 bw[4][8];
    #pragma unroll
    for (int j = 0; j < 4; ++j)
        #pragma unroll
        for (int ksl = 0; ksl < 8; ++ksl)
            bw[j][ksl] = ((const s16x8*)PW2)[(((s * 8 + cg * 4 + j) * 32) + kq * 8 + ksl) * 64 + lane];

    const int erow = tid >> 4, ejp = tid & 15;
    const int lgr = w & 3;
    float b2v[8];
    #pragma unroll
    for (int q = 0; q < 8; ++q) {
        int dj = q & 1, gq = q >> 1;
        b2v[q] = b2[gq * 512 + s * 32 + ejp * 2 + dj];
    }
    float woA0 = w_out[s * 32 + ejp * 2], woA1 = w_out[s * 32 + ejp * 2 + 1];
    float woB0 = w_out[512 + s * 32 + ejp * 2], woB1 = w_out[512 + s * 32 + ejp * 2 + 1];

    // staging decompose: LDS addr = p*8192 + tid*16 ; ks = p*4 + (tid>>7)
    const int sl15 = tid & 15, slg = (tid >> 4) & 3, srh = (tid >> 6) & 1, skq = tid >> 7;
    const int sgrow = srh * 16 + sl15;

    uint4 nv[8];
    #pragma unroll
    for (int p = 0; p < 8; ++p) {
        int ks = p * 4 + skq;
        const unsigned short* src = (p < 4) ? h1C : h2R;
        int kel = (p < 4) ? ks : (ks - 16);
        nv[p] = *(const uint4*)(src + (size_t)(m0 + sgrow) * HID + kel * 32 + slg * 8);
    }
    #pragma unroll
    for (int p = 0; p < 8; ++p)
        *(uint4*)((char*)Ab + p * 8192 + tid * 16) = nv[p];

    #pragma unroll 1
    for (int ch = 0; ch < 64; ++ch) {
        __syncthreads();   // (a) Ab ready; prev epilogue done

        if (ch < 63) {
            #pragma unroll
            for (int p = 0; p < 8; ++p) {
                int ks = p * 4 + skq;
                const unsigned short* src = (p < 4) ? h1C : h2R;
                int kel = (p < 4) ? ks : (ks - 16);
                nv[p] = *(const uint4*)(src + (size_t)(m0 + (ch + 1) * 32 + sgrow) * HID + kel * 32 + slg * 8);
            }
        }

        // K-loop: both rh tiles, 4 ct tiles, K-quarter kq
        f32x4 acc[2][4];
        #pragma unroll
        for (int rh = 0; rh < 2; ++rh)
            #pragma unroll
            for (int j = 0; j < 4; ++j) { acc[rh][j][0]=0.f; acc[rh][j][1]=0.f; acc[rh][j][2]=0.f; acc[rh][j][3]=0.f; }
        #pragma unroll
        for (int ksl = 0; ksl < 8; ++ksl) {
            int ks = kq * 8 + ksl;
            s16x8 a0 = *(const s16x8*)((const char*)Ab + ks * 2048 + lane * 16);
            s16x8 a1 = *(const s16x8*)((const char*)Ab + ks * 2048 + 1024 + lane * 16);
            #pragma unroll
            for (int j = 0; j < 4; ++j) {
                acc[0][j] = __builtin_amdgcn_mfma_f32_16x16x32_bf16(a0, bw[j][ksl], acc[0][j], 0, 0, 0);
                acc[1][j] = __builtin_amdgcn_mfma_f32_16x16x32_bf16(a1, bw[j][ksl], acc[1][j], 0, 0, 0);
            }
        }

        // tree-merge into gl[copy]: kq odd writes, kq even adds
        if (!adder) {
            #pragma unroll
            for (int j = 0; j < 4; ++j) {
                int col = (cg * 4 + j) * 16 + l15;
                int u = col & 31, gate = col >> 5;
                float* dst = &gl[copy][u & 1][(u >> 1) * 4 + (gate ^ lg)];
                #pragma unroll
                for (int rh = 0; rh < 2; ++rh)
                    #pragma unroll
                    for (int r = 0; r < 4; ++r)
                        dst[(rh * 16 + lg * 4 + r) * 64] = acc[rh][j][r];
            }
        }
        __syncthreads();   // (b) partial copies written
        if (adder) {
            #pragma unroll
            for (int j = 0; j < 4; ++j) {
                int col = (cg * 4 + j) * 16 + l15;
                int u = col & 31, gate = col >> 5;
                float* dst = &gl[copy][u & 1][(u >> 1) * 4 + (gate ^ lg)];
                #pragma unroll
                for (int rh = 0; rh < 2; ++rh)
                    #pragma unroll
                    for (int r = 0; r < 4; ++r)
                        dst[(rh * 16 + lg * 4 + r) * 64] += acc[rh][j][r];
            }
        }
        __syncthreads();   // (c) gl final

        if (ch < 63) {
            #pragma unroll
            for (int p = 0; p < 8; ++p)
                *(uint4*)((char*)Ab + p * 8192 + tid * 16) = nv[p];
        }

        // epilogue
        {
            int m = m0 + ch * 32 + erow;
            int gbase = erow * 64 + ejp * 4;
            f32x4 qa = *(const f32x4*)&gl[0][0][gbase];
            qa += *(const f32x4*)&gl[1][0][gbase];
            f32x4 qb = *(const f32x4*)&gl[0][1][gbase];
            qb += *(const f32x4*)&gl[1][1][gbase];
            qa = deperm(qa, lgr); qb = deperm(qb, lgr);

            int cix = m * HID + s * 32 + ejp * 2;
            unsigned cp = *(const unsigned*)(c2s + cix);
            float cold0 = bf2f(cp & 0xffffu), cold1 = bf2f(cp >> 16);
            float i0 = sigm(qa[0] + b2v[0]);
            float f0 = sigm(qa[1] + b2v[2]);
            float g0 = tanh_(qa[2] + b2v[4]);
            float o0 = sigm(qa[3] + b2v[6]);
            float cn0 = f0 * cold0 + i0 * g0;
            float hn0 = o0 * tanh_(cn0);
            float i1 = sigm(qb[0] + b2v[1]);
            float f1 = sigm(qb[1] + b2v[3]);
            float g1 = tanh_(qb[2] + b2v[5]);
            float o1 = sigm(qb[3] + b2v[7]);
            float cn1 = f1 * cold1 + i1 * g1;
            float hn1 = o1 * tanh_(cn1);
            *(unsigned*)(c2s + cix) = (unsigned)f2bf(cn0) | ((unsigned)f2bf(cn1) << 16);
            *(unsigned*)(h2W + cix) = (unsigned)f2bf(hn0) | ((unsigned)f2bf(hn1) << 16);

            // per-slice output partial (NO atomics): reduce 16 ejp lanes
            float p0 = hn0 * woA0 + hn1 * woA1;
            float p1 = hn0 * woB0 + hn1 * woB1;
            #pragma unroll
            for (int d = 1; d < 16; d <<= 1) {
                p0 += __shfl_xor(p0, d, 16);
                p1 += __shfl_xor(p1, d, 16);
            }
            if (ejp == 0)
                *(float2*)(pp + (((size_t)(g * 16 + s)) << 12) + (size_t)(ch * 32 + erow) * 2)
                    = make_float2(p0, p1);
        }
    }
}

// ---------------- final-step output: out[:,59] = sum_s pp + b_out ----------------
__global__ void tail_kernel(const float* __restrict__ pp, const float* __restrict__ b_out,
                            float* __restrict__ outp)
{
    int i = blockIdx.x * 256 + threadIdx.x;
    if (i < 65536) {
        int m = i >> 1, j = i & 1;
        int g = m >> 11;
        int idx = (m & 2047) * 2 + j;
        float sum = b_out[j];
        #pragma unroll 1
        for (int s = 0; s < 16; ++s)
            sum += pp[(((size_t)(g * 16 + s)) << 12) + idx];
        outp[(size_t)m * (2 * NSTEP) + (NSTEP - 1) * 2 + j] = sum;
    }
}

extern "C" void kernel_launch(void* const* d_in, const int* in_sizes, int n_in,
                              void* d_out, int out_size, void* d_ws, size_t ws_size,
                              hipStream_t stream)
{
    (void)in_sizes; (void)n_in; (void)out_size; (void)ws_size;
    const float* h        = (const float*)d_in[0];
    const float* w_init_h = (const float*)d_in[1];
    const float* b_init_h = (const float*)d_in[2];
    const float* w_init_c = (const float*)d_in[3];
    const float* b_init_c = (const float*)d_in[4];
    const float* w_ih0    = (const float*)d_in[5];
    const float* w_hh0    = (const float*)d_in[6];
    const float* b_ih0    = (const float*)d_in[7];
    const float* b_hh0    = (const float*)d_in[8];
    const float* w_ih1    = (const float*)d_in[9];
    const float* w_hh1    = (const float*)d_in[10];
    const float* b_ih1    = (const float*)d_in[11];
    const float* b_hh1    = (const float*)d_in[12];
    const float* w_out    = (const float*)d_in[13];
    const float* b_out    = (const float*)d_in[14];
    float* out = (float*)d_out;

    char* ws = (char*)d_ws;
    unsigned short* h1s[2] = { (unsigned short*)(ws + 0),
                               (unsigned short*)(ws + 33554432) };
    unsigned short* h2s[2] = { (unsigned short*)(ws + 67108864),
                               (unsigned short*)(ws + 100663296) };
    unsigned short* c1s = (unsigned short*)(ws + 134217728);
    unsigned short* c2s = (unsigned short*)(ws + 167772160);
    float* pp           = (float*)(ws + 201326592);   // 4 MB
    unsigned short* PW1 = (unsigned short*)(ws + 205520896);
    unsigned short* PW2 = (unsigned short*)(ws + 207618048);
    unsigned short* PI  = (unsigned short*)(ws + 211812352);
    float* b1 = (float*)(ws + 212860928);
    float* b2 = (float*)(ws + 212869120);

    pack_kernel<<<14352, 256, 0, stream>>>(w_hh0, w_ih1, w_hh1, w_init_h, w_init_c,
                                           b_ih0, b_hh0, b_ih1, b_hh1, PW1, PW2, PI, b1, b2);
    init_kernel<<<32768 / BMI, TPB, 0, stream>>>(h, PI, b_init_h, b_init_c,
                                                 h1s[1], h2s[1], c1s, c2s);
    for (int t = 0; t < NSTEP; ++t) {
        const unsigned short* h1R = h1s[(t + 1) & 1];
        unsigned short* h1W = h1s[t & 1];
        const unsigned short* h2R = h2s[(t + 1) & 1];
        unsigned short* h2W = h2s[t & 1];
        l1_kernel<<<256, TPB, 0, stream>>>(h1R, h1W, c1s, pp, out, PW1, b1, w_ih0, b_out, t);
        l2_kernel<<<256, TPB, 0, stream>>>(h1W, h2R, h2W, c2s, pp, PW2, b2, w_out);
    }
    tail_kernel<<<256, 256, 0, stream>>>(pp, b_out, out);
}